// Round 6
// baseline (123.773 us; speedup 1.0000x reference)
//
#include <hip/hip_runtime.h>

// VectorQuantizer: B=32768, D=256, K=16
// out layout (all f32): [0, B*D) z_q ; [B*D] vq_loss ; [B*D+1, 2*B*D+1) indices (as float)

constexpr int Bn = 32768;
constexpr int Dn = 256;
constexpr int Kn = 16;
constexpr int NQUAD = Bn * Dn / 4;            // 2,097,152 quads
constexpr int GRID = 2048;
constexpr int BLOCK = 256;
constexpr int QPT = NQUAD / (GRID * BLOCK);   // exactly 4 quads/thread
constexpr int ROWP = 260;                     // padded cbt row: bank stride 4, 1040B row (16B-aligned)
constexpr float LOSS_SCALE = 1.25f / (float)Bn;  // (1 + 0.25) * (1/B)

__global__ void vq_init_loss(float* out) {
    if (threadIdx.x == 0) out[(size_t)Bn * Dn] = 0.0f;
}

__global__ __launch_bounds__(BLOCK) void vq_main(const float* __restrict__ z,
                                                 const float* __restrict__ cb,
                                                 float* __restrict__ out) {
    // codebook transposed into LDS: cbt[k*ROWP + d]; ROWP=260 breaks the
    // 16-way staging-write bank conflict (256 mod 32 == 0 put lanes 0..15 on one bank)
    __shared__ float cbt[Kn * ROWP];
    __shared__ float wsum[4];
    for (int i = threadIdx.x; i < Kn * Dn; i += BLOCK) {
        int d = i >> 4;        // codebooks is (D, K) row-major
        int k = i & (Kn - 1);
        cbt[k * ROWP + d] = cb[i];
    }
    __syncthreads();

    float* __restrict__ zq   = out;
    float* __restrict__ idxf = out + (size_t)Bn * Dn + 1;

    const int tid = blockIdx.x * BLOCK + threadIdx.x;
    const int stride = GRID * BLOCK;
    const int d0 = (tid * 4) & (Dn - 1);   // same for all 4 iterations (4*stride % 256 == 0)

    // Issue all 4 global loads up front: 4x memory-level parallelism per wave.
    float4 zv[QPT];
    #pragma unroll
    for (int it = 0; it < QPT; ++it)
        zv[it] = *reinterpret_cast<const float4*>(z + (size_t)(tid + it * stride) * 4);

    float acc = 0.0f;
    #pragma unroll
    for (int it = 0; it < QPT; ++it) {
        const int f = (tid + it * stride) * 4;
        const float zz[4] = {zv[it].x, zv[it].y, zv[it].z, zv[it].w};

        float best[4] = {1e30f, 1e30f, 1e30f, 1e30f};
        int   bi[4]   = {0, 0, 0, 0};

        #pragma unroll
        for (int k = 0; k < Kn; ++k) {
            const float4 c = *reinterpret_cast<const float4*>(&cbt[k * ROWP + d0]);
            const float cc[4] = {c.x, c.y, c.z, c.w};
            #pragma unroll
            for (int j = 0; j < 4; ++j) {
                float dd = zz[j] - cc[j];
                float d2 = dd * dd;              // exact same expression as reference -> same rounding
                bi[j]   = (d2 < best[j]) ? k : bi[j];   // strict <: first-min tie-break (jnp.argmin)
                best[j] = fminf(best[j], d2);
            }
        }

        // z_q via LDS lookup (bit-identical to tracking the code in-loop, saves 64 cndmask/quad)
        float bc[4];
        #pragma unroll
        for (int j = 0; j < 4; ++j)
            bc[j] = cbt[bi[j] * ROWP + d0 + j];

        *reinterpret_cast<float4*>(zq + f) = make_float4(bc[0], bc[1], bc[2], bc[3]);

        // indices region starts at B*D+1 (4B-misaligned): scalar stores, L2 merges lines
        idxf[f + 0] = (float)bi[0];
        idxf[f + 1] = (float)bi[1];
        idxf[f + 2] = (float)bi[2];
        idxf[f + 3] = (float)bi[3];

        acc += best[0] + best[1] + best[2] + best[3];
    }

    // wave reduce (64 lanes)
    #pragma unroll
    for (int off = 32; off > 0; off >>= 1)
        acc += __shfl_down(acc, off, 64);

    const int lane = threadIdx.x & 63;
    const int wid  = threadIdx.x >> 6;
    if (lane == 0) wsum[wid] = acc;
    __syncthreads();
    if (threadIdx.x == 0) {
        float s = (wsum[0] + wsum[1] + wsum[2] + wsum[3]) * LOSS_SCALE;
        atomicAdd(out + (size_t)Bn * Dn, s);
    }
}

extern "C" void kernel_launch(void* const* d_in, const int* in_sizes, int n_in,
                              void* d_out, int out_size, void* d_ws, size_t ws_size,
                              hipStream_t stream) {
    const float* z  = (const float*)d_in[0];
    const float* cb = (const float*)d_in[1];
    float* out = (float*)d_out;

    vq_init_loss<<<1, 64, 0, stream>>>(out);
    vq_main<<<GRID, BLOCK, 0, stream>>>(z, cb, out);
}